// Round 3
// baseline (169.717 us; speedup 1.0000x reference)
//
#include <hip/hip_runtime.h>
#include <hip/hip_bf16.h>

#define NB 4
#define CCH 256
#define CRD 32
#define NN 4096

typedef __attribute__((ext_vector_type(8))) short short8;
typedef __attribute__((ext_vector_type(4))) float floatx4;
typedef __attribute__((ext_vector_type(4))) int intx4;
typedef __attribute__((ext_vector_type(2))) unsigned int uintx2;

__device__ __forceinline__ unsigned short f2bf(float f) {
  unsigned u = __builtin_bit_cast(unsigned, f);
  u += 0x7FFFu + ((u >> 16) & 1u);
  return (unsigned short)(u >> 16);
}

// Clamped convert: finite bf16 regardless of input (NaN -> -1e4 via IEEE
// maxNum/minNum, +-inf -> +-1e4). Legit qkv values |v| < ~20: transparent.
__device__ __forceinline__ unsigned short f2bf_c(float f) {
  f = fminf(fmaxf(f, -1.0e4f), 1.0e4f);
  unsigned u = __builtin_bit_cast(unsigned, f);
  u += 0x7FFFu + ((u >> 16) & 1u);
  return (unsigned short)(u >> 16);
}

__device__ __forceinline__ unsigned pack2c(float a, float b) {
  return (unsigned)f2bf_c(a) | ((unsigned)f2bf_c(b) << 16);
}

// Output sanitizer: NaN -> -1e30 (IEEE maxNum), +-inf -> +-1e30.
__device__ __forceinline__ float sat(float v) {
  return fminf(fmaxf(v, -1.0e30f), 1.0e30f);
}

__device__ __forceinline__ short8 ld_frag_g(const unsigned short* p) {
  return __builtin_bit_cast(short8, *(const intx4*)p);
}

// ---------------------------------------------------------------------------
// Kernel 1: fused transpose + QKV GEMM. Round-14 change: W conversion fp32->
// bf16 is done in-block during LDS staging (w_convert kernel + Wb scratch
// eliminated -> one less launch + drain). Per (n-block, m-group, b): stage
// x[256c x 64n] transposed into LDS once, loop m-tiles of W.
//   mg=0: m-tiles 0..2 (q,k + v rows 0..127); mg=1: m-tiles 3..4 (v 128..255)
// ---------------------------------------------------------------------------
__global__ __launch_bounds__(256) void gemm_qkv_fused(
    const float* __restrict__ x,
    const float* __restrict__ Wq, const float* __restrict__ bq,
    const float* __restrict__ Wk, const float* __restrict__ bk,
    const float* __restrict__ Wv, const float* __restrict__ bv,
    unsigned short* __restrict__ qT, unsigned short* __restrict__ kT,
    unsigned short* __restrict__ vv)
{
  __shared__ __align__(16) unsigned short xs[64 * 264];
  __shared__ __align__(16) unsigned short ws[64 * 264];

  const int tid  = threadIdx.x;
  const int wave = tid >> 6;          // n-fragment 0..3 (16 n each)
  const int lane = tid & 63;
  const int lq   = lane >> 4;
  const int lm   = lane & 15;
  const int n0   = blockIdx.x << 6;
  const int mg   = blockIdx.y;
  const int b    = blockIdx.z;

  // stage x[b][0:256][n0:n0+64] -> xs[n][c] bf16 (transpose + convert).
  {
    const int nn = lane;
    const int cg = wave;
    const float* xb = x + ((size_t)b << 20) + n0 + nn;
#pragma unroll
    for (int it = 0; it < 16; ++it) {
      const int c0 = it * 16 + cg * 4;
      const float v0 = xb[(size_t)(c0 + 0) << 12];
      const float v1 = xb[(size_t)(c0 + 1) << 12];
      const float v2 = xb[(size_t)(c0 + 2) << 12];
      const float v3 = xb[(size_t)(c0 + 3) << 12];
      uintx2 u;
      u[0] = pack2c(v0, v1);
      u[1] = pack2c(v2, v3);
      *(uintx2*)(xs + nn * 264 + c0) = u;
    }
  }

  const int mt_lo = mg ? 3 : 0;
  const int mt_hi = mg ? 5 : 3;

  for (int mt = mt_lo; mt < mt_hi; ++mt) {
    // stage W rows [mt*64, mt*64+64) fp32 -> bf16 into ws (float4 loads)
#pragma unroll
    for (int i = 0; i < 16; ++i) {
      const int u  = i * 256 + tid;
      const int m  = u >> 6;
      const int o4 = (u & 63) * 4;
      const float* src = (mt == 0)
          ? (m < 32 ? Wq + (size_t)m * CCH : Wk + (size_t)(m - 32) * CCH)
          : Wv + (size_t)((mt - 1) * 64 + m) * CCH;
      const floatx4 f = *(const floatx4*)(src + o4);
      uintx2 uu;
      uu[0] = pack2c(f[0], f[1]);
      uu[1] = pack2c(f[2], f[3]);
      *(uintx2*)(ws + m * 264 + o4) = uu;
    }
    __syncthreads();   // xs (first iter) + ws ready

    floatx4 acc[4];
#pragma unroll
    for (int t = 0; t < 4; ++t) acc[t] = (floatx4){0.f, 0.f, 0.f, 0.f};

#pragma unroll
    for (int k0 = 0; k0 < 8; ++k0) {
      short8 af[4];
#pragma unroll
      for (int ms = 0; ms < 4; ++ms)
        af[ms] = __builtin_bit_cast(short8,
            *(const intx4*)(ws + (ms * 16 + lm) * 264 + k0 * 32 + lq * 8));
      const short8 bf = __builtin_bit_cast(short8,
          *(const intx4*)(xs + (wave * 16 + lm) * 264 + k0 * 32 + lq * 8));
#pragma unroll
      for (int ms = 0; ms < 4; ++ms)
        acc[ms] = __builtin_amdgcn_mfma_f32_16x16x32_bf16(af[ms], bf,
                                                          acc[ms], 0, 0, 0);
    }
    __syncthreads();   // all ws/xs reads of this mt complete

    if (mt == 0) {
      // q/k epilogue: rows 0..31 = q, 32..63 = k (register-only; no LDS)
      const int n = n0 + wave * 16 + lm;
#pragma unroll
      for (int ms = 0; ms < 4; ++ms) {
        const int d0 = (ms & 1) * 16 + lq * 4;
        const float* bias = (ms < 2) ? bq : bk;
        unsigned short* dst = (ms < 2) ? qT : kT;
        uintx2 u;
        u[0] = pack2c(acc[ms][0] + bias[d0],     acc[ms][1] + bias[d0 + 1]);
        u[1] = pack2c(acc[ms][2] + bias[d0 + 2], acc[ms][3] + bias[d0 + 3]);
        *(uintx2*)(dst + (size_t)(b * NN + n) * CRD + d0) = u;
      }
    } else {
      // V epilogue: bounce through ws ([64c][64n] bf16) for coalesced stores
      const int cb = (mt - 1) * 64;
      unsigned short* vb2 = ws;
#pragma unroll
      for (int ms = 0; ms < 4; ++ms)
#pragma unroll
        for (int r = 0; r < 4; ++r) {
          const int c = ms * 16 + lq * 4 + r;
          vb2[c * 64 + wave * 16 + lm] = f2bf_c(acc[ms][r] + bv[cb + c]);
        }
      __syncthreads();
#pragma unroll
      for (int it = 0; it < 2; ++it) {
        const int u = it * 256 + tid;
        const int m = u >> 3;
        const int o = (u & 7) * 8;
        *(intx4*)(vv + (size_t)(b * CCH + cb + m) * NN + n0 + o) =
            *(const intx4*)(vb2 + m * 64 + o);
      }
      __syncthreads();  // vb2 reads done before next mt restages ws
    }
  }
}

// ---------------------------------------------------------------------------
// Kernel 2: attention. Round-14 change: 512-thread / 64-row blocks (1/CU)
// -> 256-thread / 32-row blocks, TWO blocks per CU (LDS 74.2 KB/block).
// Per-CU arithmetic identical (same MFMA / exp / LDS-read totals; V staging
// doubles but is L2-resident). The two blocks' barriers are independent, so
// one block's barrier/L2-latency stalls overlap the other's compute --
// attacks the measured >50% stall fraction (MfmaUtil 18 + VALUBusy 27).
// ---------------------------------------------------------------------------
__global__ __launch_bounds__(256) void attn_kernel(
    const float* __restrict__ x, const float* __restrict__ gamma_p,
    const unsigned short* __restrict__ qT, const unsigned short* __restrict__ kT,
    const unsigned short* __restrict__ vv, float* __restrict__ out)
{
  // [0,65536): V double buffer (2 x 256c x 64j bf16, swizzled)
  // [65536, +8704): P double buffer (2 parity x 32 i x 68col shorts)
  __shared__ __align__(16) unsigned char smem[65536 + 2 * 4352];

  const int tid  = threadIdx.x;
  const int cs   = tid >> 6;    // c-quarter (64 cols) AND j-tile for QK
  const int lane = tid & 63;
  const int lq   = lane >> 4;
  const int lm   = lane & 15;
  const int xcd = blockIdx.x & 7;
  const int p   = blockIdx.x >> 3;     // 0..63
  const int b   = xcd >> 1;
  const int i0  = (((xcd & 1) << 6) | p) << 5;   // 32-row block

  const unsigned short* kTb = kT + (size_t)b * NN * CRD;
  const unsigned short* vb  = vv + (size_t)b * CCH * NN;

  short8 qf[2];
#pragma unroll
  for (int f = 0; f < 2; ++f)
    qf[f] = ld_frag_g(qT + (size_t)(b * NN + i0 + f * 16 + lm) * CRD + lq * 8);

  // per-lane V-stage coordinates: unit u = m*256+tid; c = u>>3; jb = u&7
  int vs_g[8];
  int vs_off[8];
#pragma unroll
  for (int m = 0; m < 8; ++m) {
    const int u  = m * 256 + tid;
    const int c  = u >> 3;
    const int jb = u & 7;
    vs_g[m]   = c * NN + jb * 8;                 // + j0 at load time
    vs_off[m] = c * 128 + ((jb ^ (c & 7)) * 16); // swizzled LDS slot
  }

  floatx4 acc[8];                                // [f*4 + nt]
#pragma unroll
  for (int t = 0; t < 8; ++t) acc[t] = (floatx4){0.f, 0.f, 0.f, 0.f};
  float lsum[8] = {0.f, 0.f, 0.f, 0.f, 0.f, 0.f, 0.f, 0.f};  // [f*4 + r]

  // prologue: prefetch chunk 0 (this wave's j-tile = cs)
  intx4 vreg[8];
#pragma unroll
  for (int m = 0; m < 8; ++m)
    vreg[m] = *(const intx4*)(vb + vs_g[m]);
  short8 kf = ld_frag_g(kTb + (size_t)(cs * 16 + lm) * CRD + lq * 8);

  const floatx4 zf = {0.f, 0.f, 0.f, 0.f};

#pragma unroll 1
  for (int k = 0; k < 64; ++k) {
    unsigned char* vbuf = smem + ((k & 1) << 15);
    unsigned char* pb   = smem + 65536 + (k & 1) * 4352;

    // phase 1a: stage prefetched V(k) into LDS parity k (race-free: barrier
    // A(k-1) guarantees all waves finished PV(k-2) reads of this buffer)
#pragma unroll
    for (int m = 0; m < 8; ++m)
      *(intx4*)(vbuf + vs_off[m]) = vreg[m];

    // phase 1b: S rows for BOTH i-frags, this wave's 16-j tile (jt = cs)
#pragma unroll
    for (int f = 0; f < 2; ++f) {
      floatx4 S = __builtin_amdgcn_mfma_f32_16x16x32_bf16(qf[f], kf, zf, 0, 0, 0);
#pragma unroll
      for (int r = 0; r < 4; ++r) {
        const float pv = __expf(fminf(fmaxf(S[r], -40.f), 40.f));
        lsum[f * 4 + r] += pv;
        *(unsigned short*)(pb + (f * 16 + lq * 4 + r) * 136 +
                           ((cs * 16 + lm) << 1)) = f2bf(pv);
      }
    }

    __syncthreads();  // A: V(k) + full P(k) visible to all waves

    // prefetch chunk k+1 into registers (consumed next iteration)
    if (k < 63) {
      const int j0n = (k + 1) << 6;
#pragma unroll
      for (int m = 0; m < 8; ++m)
        vreg[m] = *(const intx4*)(vb + vs_g[m] + j0n);
      kf = ld_frag_g(kTb + (size_t)(j0n + cs * 16 + lm) * CRD + lq * 8);
    }

    // phase 2: PV over this wave's 64-col c-quarter; each V frag feeds 2
    // P frags (i-frags). setprio: favor MFMA-issuing wave vs the co-resident
    // block's staging waves (T5 regime: independent blocks = role diversity).
    __builtin_amdgcn_s_setprio(1);
#pragma unroll
    for (int ks = 0; ks < 2; ++ks) {
      short8 pf[2];
#pragma unroll
      for (int f = 0; f < 2; ++f) {
        const unsigned char* pa = pb + (f * 16 + lm) * 136 + ks * 64 + lq * 16;
        struct U128 { unsigned long long a, b; } pp;
        pp.a = *(const unsigned long long*)pa;
        pp.b = *(const unsigned long long*)(pa + 8);
        pf[f] = __builtin_bit_cast(short8, pp);
      }
#pragma unroll
      for (int nt = 0; nt < 4; ++nt) {
        const int c = cs * 64 + nt * 16 + lm;
        const short8 vf = __builtin_bit_cast(
            short8,
            *(const intx4*)(vbuf + c * 128 + (((ks * 4 + lq) ^ (lm & 7)) * 16)));
#pragma unroll
        for (int f = 0; f < 2; ++f)
          acc[f * 4 + nt] = __builtin_amdgcn_mfma_f32_16x16x32_bf16(
              pf[f], vf, acc[f * 4 + nt], 0, 0, 0);
      }
    }
    __builtin_amdgcn_s_setprio(0);
    // no trailing barrier: iter k+1 writes parity k+1 buffers
  }

  // reduce lsum across the 16 lm lanes (each lane then holds the row-sum
  // partial of its (f,lq,r) row for this wave's j-tiles)
#pragma unroll
  for (int e = 0; e < 8; ++e) {
    float v = lsum[e];
    v += __shfl_xor(v, 1);
    v += __shfl_xor(v, 2);
    v += __shfl_xor(v, 4);
    v += __shfl_xor(v, 8);
    lsum[e] = v;
  }
  __syncthreads();  // all PV(63) reads (parity-1 area) issued; reuse parity-0
  float* lbuf = (float*)smem;
  {
    const int base = (cs * 64 + lane) * 8;
#pragma unroll
    for (int e = 0; e < 8; ++e) lbuf[base + e] = lsum[e];
  }
  __syncthreads();
  float inv[8];
#pragma unroll
  for (int e = 0; e < 8; ++e) {
    float v = 0.f;
#pragma unroll
    for (int q = 0; q < 4; ++q)
      v += lbuf[(q * 64 + lane) * 8 + e];
    inv[e] = 1.0f / v;
  }

  const float gm = gamma_p[0];
#pragma unroll
  for (int f = 0; f < 2; ++f)
#pragma unroll
    for (int nt = 0; nt < 4; ++nt) {
      const int c = cs * 64 + nt * 16 + lm;
      const int i = i0 + f * 16 + lq * 4;
      const size_t idx = (size_t)(b * CCH + c) * NN + i;
      const floatx4 xv = *(const floatx4*)(x + idx);
      floatx4 o;
#pragma unroll
      for (int r = 0; r < 4; ++r)
        o[r] = gm * sat(acc[f * 4 + nt][r] * inv[f * 4 + r]) + xv[r];
      *(floatx4*)(out + idx) = o;
    }
}

extern "C" void kernel_launch(void* const* d_in, const int* in_sizes, int n_in,
                              void* d_out, int out_size, void* d_ws, size_t ws_size,
                              hipStream_t stream) {
  (void)in_sizes; (void)n_in; (void)out_size; (void)ws_size;
  const float* x     = (const float*)d_in[0];
  const float* Wq    = (const float*)d_in[1];
  const float* bq    = (const float*)d_in[2];
  const float* Wk    = (const float*)d_in[3];
  const float* bk    = (const float*)d_in[4];
  const float* Wv    = (const float*)d_in[5];
  const float* bv    = (const float*)d_in[6];
  const float* gamma = (const float*)d_in[7];

  unsigned short* qT = (unsigned short*)d_ws;              // 1 MiB
  unsigned short* kT = qT + (size_t)NB * NN * CRD;         // 1 MiB
  unsigned short* vv = kT + (size_t)NB * NN * CRD;         // 8 MiB

  gemm_qkv_fused<<<dim3(64, 2, 4), 256, 0, stream>>>(x, Wq, bq, Wk, bk, Wv, bv,
                                                     qT, kT, vv);
  attn_kernel<<<dim3(512, 1, 1), 256, 0, stream>>>(x, gamma, qT, kT, vv,
                                                   (float*)d_out);
}